// Round 8
// baseline (29.155 us; speedup 1.0000x reference)
//
#include <hip/hip_runtime.h>

#define NBAS  256
#define NORB  128
#define NROWS 65536
#define WPB   4                      // waves per block
#define RPW   4                      // rows per wave
#define ROWS_PER_BLOCK (WPB * RPW)   // 16

// canonical gfx9 wave64 inclusive prefix scan — 6 dependent VALU adds (DPP),
// HW-validated rounds 3/5/7 (absmax 9.8e-4)
__device__ __forceinline__ float wave_scan_incl(float x) {
    int t;
    t = __builtin_amdgcn_update_dpp(0, __float_as_int(x), 0x111, 0xf, 0xf, false); // row_shr:1
    x += __int_as_float(t);
    t = __builtin_amdgcn_update_dpp(0, __float_as_int(x), 0x112, 0xf, 0xf, false); // row_shr:2
    x += __int_as_float(t);
    t = __builtin_amdgcn_update_dpp(0, __float_as_int(x), 0x114, 0xf, 0xf, false); // row_shr:4
    x += __int_as_float(t);
    t = __builtin_amdgcn_update_dpp(0, __float_as_int(x), 0x118, 0xf, 0xf, false); // row_shr:8
    x += __int_as_float(t);
    t = __builtin_amdgcn_update_dpp(0, __float_as_int(x), 0x142, 0xa, 0xf, false); // row_bcast:15
    x += __int_as_float(t);
    t = __builtin_amdgcn_update_dpp(0, __float_as_int(x), 0x143, 0xc, 0xf, false); // row_bcast:31
    x += __int_as_float(t);
    return x;
}

__device__ __forceinline__ float bcast63(float x) {   // lane63 -> all (uniform)
    return __int_as_float(__builtin_amdgcn_readlane(__float_as_int(x), 63));
}

// ws4 layout: 8 float4 slots x 64 lanes, slot k at ws4[k*64 + ln]:
//  k0 {nex0..3}  k1 {lcc0..3}  k2 {cx0..3}  k3 {cy0..3}  k4 {cz0..3}
//  k5 {a0,a1,a2,a3}  k6 {b0,b1,b2,b3}  k7 {c9, st0, st1, st2 (ints bitcast)}
__global__ void setup_kernel(
    const float* __restrict__ atom_coords,
    const float* __restrict__ bas_exp,
    const float* __restrict__ bas_coeffs,
    const float* __restrict__ norm_cst,
    const int*   __restrict__ bas_l,
    const int*   __restrict__ bas_m,
    const int*   __restrict__ bas_atom_index,
    const int*   __restrict__ index_ctr,
    float4* __restrict__ ws4)
{
    const int ln = threadIdx.x;
    if (ln >= 64) return;
    // bases ln+64j share shell (ln mod 16) -> same (l,m)
    const int l = bas_l[ln], m = bas_m[ln];
    float nex[4], lcc[4], cx[4], cy[4], cz[4];
    #pragma unroll
    for (int j = 0; j < 4; ++j) {
        int b = ln + 64 * j;
        nex[j] = -bas_exp[b] * 1.4426950408889634f;         // -alpha*log2(e)
        lcc[j] = __log2f(norm_cst[b] * bas_coeffs[b]);      // cc>0 -> fold into exp2
        int ai = bas_atom_index[b];
        cx[j] = atom_coords[ai*3+0];
        cy[j] = atom_coords[ai*3+1];
        cz[j] = atom_coords[ai*3+2];
    }
    const float C0 = 0.2820948f, C1 = 0.4886025f, C2XY = 1.0925484f,
                C2Z2 = 0.31539156f, C2D = 0.5462742f;
    float a0=0.f,a1=0.f,a2=0.f,a3=0.f, b0=0.f,b1=0.f,b2=0.f,b3=0.f, c9=0.f;
    if (l == 0)            { a3 = C0; b3 = 1.f; }
    else if (l == 1) {
        b3 = 1.f;
        if      (m == -1) a1 = C1;
        else if (m ==  0) a2 = C1;
        else              a0 = C1;
    } else {
        if      (m == -2) { a0 = C2XY; b1 = 1.f; }                      // xy
        else if (m == -1) { a1 = C2XY; b2 = 1.f; }                      // yz
        else if (m ==  0) { a2 = 3.f*C2Z2; b2 = 1.f; c9 = -C2Z2; }      // 3z^2-r^2
        else if (m ==  1) { a2 = C2XY; b0 = 1.f; }                      // zx
        else              { a0 = C2D; a1 = C2D; b0 = 1.f; b1 = -1.f; }  // (x+y)(x-y)
    }
    int st[3];
    #pragma unroll
    for (int k = 0; k < 3; ++k) {            // lower_bound(2ln+k) over sorted index_ctr
        int o = 2*ln + k, lo = 0, hi = NBAS;
        while (lo < hi) {
            int mid = (lo + hi) >> 1;
            if (index_ctr[mid] < o) lo = mid + 1; else hi = mid;
        }
        st[k] = lo;
    }
    ws4[0*64+ln] = make_float4(nex[0],nex[1],nex[2],nex[3]);
    ws4[1*64+ln] = make_float4(lcc[0],lcc[1],lcc[2],lcc[3]);
    ws4[2*64+ln] = make_float4(cx[0],cx[1],cx[2],cx[3]);
    ws4[3*64+ln] = make_float4(cy[0],cy[1],cy[2],cy[3]);
    ws4[4*64+ln] = make_float4(cz[0],cz[1],cz[2],cz[3]);
    ws4[5*64+ln] = make_float4(a0,a1,a2,a3);
    ws4[6*64+ln] = make_float4(b0,b1,b2,b3);
    ws4[7*64+ln] = make_float4(c9, __int_as_float(st[0]),
                               __int_as_float(st[1]), __int_as_float(st[2]));
}

__global__ __launch_bounds__(256, 5) void ao_kernel(
    const float*  __restrict__ inp,    // [NROWS, 3]
    const float4* __restrict__ ws4,    // packed params
    float* __restrict__ out)           // [NROWS, NORB]
{
    __shared__ __align__(16) float s_pref[WPB][RPW][NBAS];  // wave-private prefix, 16 KB

    const int tid = threadIdx.x;
    const int w   = tid >> 6, ln = tid & 63;

    // ---- preamble: 8 coalesced dwordx4 loads, nothing else ----
    const float4 qn = ws4[0*64+ln], ql = ws4[1*64+ln];
    const float4 qx = ws4[2*64+ln], qy = ws4[3*64+ln], qz = ws4[4*64+ln];
    const float4 qa = ws4[5*64+ln], qb = ws4[6*64+ln], qc = ws4[7*64+ln];
    const float nex[4] = {qn.x,qn.y,qn.z,qn.w};
    const float lcc[4] = {ql.x,ql.y,ql.z,ql.w};
    const float cx[4]  = {qx.x,qx.y,qx.z,qx.w};
    const float cy[4]  = {qy.x,qy.y,qy.z,qy.w};
    const float cz[4]  = {qz.x,qz.y,qz.z,qz.w};
    const float a0=qa.x, a1=qa.y, a2=qa.z, a3=qa.w;
    const float b0=qb.x, b1=qb.y, b2=qb.z, b3=qb.w;
    const float c9=qc.x;
    const int st0=__float_as_int(qc.y), st1=__float_as_int(qc.z), st2=__float_as_int(qc.w);

    const int rowbase = __builtin_amdgcn_readfirstlane(
        (int)blockIdx.x * ROWS_PER_BLOCK + w * RPW);
    float* bufw = &s_pref[w][0][0];

    // ---- eval + in-register scan; first LDS touch is the prefix write ----
    #pragma unroll
    for (int r = 0; r < RPW; ++r) {
        const int row = rowbase + r;
        float px = inp[row*3+0], py = inp[row*3+1], pz = inp[row*3+2]; // uniform -> s_load
        float sc[4];
        #pragma unroll
        for (int j = 0; j < 4; ++j) {
            float x = px - cx[j], y = py - cy[j], z = pz - cz[j];
            float r2 = fmaf(x, x, fmaf(y, y, z * z));
            float A  = fmaf(a0, x, fmaf(a1, y, fmaf(a2, z, a3)));
            float Bv = fmaf(b0, x, fmaf(b1, y, fmaf(b2, z, b3)));
            float P  = fmaf(c9, r2, A * Bv);
            float E  = __builtin_exp2f(fmaf(nex[j], r2, lcc[j]));
            sc[j] = wave_scan_incl(E * P);       // 4 independent DPP chains
        }
        float t0 = bcast63(sc[0]);               // chunk totals -> uniform offsets
        float t1 = bcast63(sc[1]);
        float t2 = bcast63(sc[2]);
        float o1 = t0, o2 = t0 + t1, o3 = o2 + t2;
        float* buf = bufw + r * NBAS;
        buf[ln      ] = sc[0];
        buf[ln +  64] = sc[1] + o1;              // stride-64: 2-way bank alias = free
        buf[ln + 128] = sc[2] + o2;
        buf[ln + 192] = sc[3] + o3;
    }

    // ---- boundary diffs: 3 gathers + float2 store per row ----
    #pragma unroll
    for (int r = 0; r < RPW; ++r) {
        const float* buf = bufw + r * NBAS;
        float p0 = (st0 > 0) ? buf[st0 - 1] : 0.f;
        float p1 = (st1 > 0) ? buf[st1 - 1] : 0.f;
        float p2 = (st2 > 0) ? buf[st2 - 1] : 0.f;
        const int row = rowbase + r;
        *reinterpret_cast<float2*>(&out[(size_t)row * NORB + 2*ln]) =
            make_float2(p1 - p0, p2 - p1);
    }
}

extern "C" void kernel_launch(void* const* d_in, const int* in_sizes, int n_in,
                              void* d_out, int out_size, void* d_ws, size_t ws_size,
                              hipStream_t stream) {
    const float* inp   = (const float*)d_in[0];
    const float* atomc = (const float*)d_in[1];
    const float* bexp  = (const float*)d_in[2];
    const float* bcoef = (const float*)d_in[3];
    const float* bnorm = (const float*)d_in[4];
    // d_in[5] = bas_n (float) — redundant with bas_l, unused
    const int* bl   = (const int*)d_in[6];
    const int* bm   = (const int*)d_in[7];
    const int* bai  = (const int*)d_in[8];
    const int* ictr = (const int*)d_in[9];
    float*  out = (float*)d_out;
    float4* ws4 = (float4*)d_ws;

    hipLaunchKernelGGL(setup_kernel, dim3(1), dim3(64), 0, stream,
                       atomc, bexp, bcoef, bnorm, bl, bm, bai, ictr, ws4);
    hipLaunchKernelGGL(ao_kernel, dim3(NROWS / ROWS_PER_BLOCK), dim3(256), 0, stream,
                       inp, ws4, out);
}

// Round 9
// 22.050 us; speedup vs baseline: 1.3222x; 1.3222x over previous
//
#include <hip/hip_runtime.h>

#define NBAS  256
#define NORB  128
#define NROWS 65536
#define RPT   16                    // rows per tile
#define TILES 2                     // tiles per block (double-buffered)
#define ROWS_PER_BLOCK (RPT * TILES)

// canonical gfx9 wave64 inclusive prefix scan — 6 dependent VALU adds (DPP),
// HW-validated rounds 3/5/7 (absmax 9.8e-4)
__device__ __forceinline__ float wave_scan_incl(float x) {
    int t;
    t = __builtin_amdgcn_update_dpp(0, __float_as_int(x), 0x111, 0xf, 0xf, false); // row_shr:1
    x += __int_as_float(t);
    t = __builtin_amdgcn_update_dpp(0, __float_as_int(x), 0x112, 0xf, 0xf, false); // row_shr:2
    x += __int_as_float(t);
    t = __builtin_amdgcn_update_dpp(0, __float_as_int(x), 0x114, 0xf, 0xf, false); // row_shr:4
    x += __int_as_float(t);
    t = __builtin_amdgcn_update_dpp(0, __float_as_int(x), 0x118, 0xf, 0xf, false); // row_shr:8
    x += __int_as_float(t);
    t = __builtin_amdgcn_update_dpp(0, __float_as_int(x), 0x142, 0xa, 0xf, false); // row_bcast:15
    x += __int_as_float(t);
    t = __builtin_amdgcn_update_dpp(0, __float_as_int(x), 0x143, 0xc, 0xf, false); // row_bcast:31
    x += __int_as_float(t);
    return x;
}

__global__ __launch_bounds__(256, 4) void ao_kernel(
    const float* __restrict__ inp,            // [NROWS, 3]
    const float* __restrict__ atom_coords,    // [16, 3]
    const float* __restrict__ bas_exp,        // [NBAS]
    const float* __restrict__ bas_coeffs,     // [NBAS]
    const float* __restrict__ norm_cst,       // [NBAS]
    const int*   __restrict__ bas_l,          // [NBAS]
    const int*   __restrict__ bas_m,          // [NBAS]
    const int*   __restrict__ bas_atom_index, // [NBAS]
    const int*   __restrict__ index_ctr,      // [NBAS] sorted
    float* __restrict__ out)                  // [NROWS, NORB]
{
    __shared__ __align__(16) float s_vals[TILES][RPT][NBAS];  // 32 KB double buffer
    __shared__ int s_start[NORB + 1];

    const int tid = threadIdx.x;

    // ---- per-thread basis params: coalesced, register-resident ----
    float ex = bas_exp[tid];
    float cc = norm_cst[tid] * bas_coeffs[tid];
    int   l  = bas_l[tid];
    int   m  = bas_m[tid];
    int   ai = bas_atom_index[tid];
    float cx = atom_coords[ai*3+0], cy = atom_coords[ai*3+1], cz = atom_coords[ai*3+2];

    // start[] without binsearch: thread j fills o in (idx[j-1], idx[j]]
    int ic   = index_ctr[tid];
    int prev = (tid == 0) ? -1 : index_ctr[tid - 1];
    for (int o = prev + 1; o <= ic; ++o) s_start[o] = tid;
    if (tid == NBAS - 1)
        for (int o = ic + 1; o <= NORB; ++o) s_start[o] = NBAS;

    // fold spherical constant + cc into bilinear: P = (a.[x,y,z,1])(b.[x,y,z,1]) + c9*r2
    const float C0 = 0.2820948f, C1 = 0.4886025f, C2XY = 1.0925484f,
                C2Z2 = 0.31539156f, C2D = 0.5462742f;
    float a0=0.f,a1=0.f,a2=0.f,a3=0.f, b0=0.f,b1=0.f,b2=0.f,b3=0.f, c9=0.f;
    if (l == 0)            { a3 = cc*C0; b3 = 1.f; }
    else if (l == 1) {
        float s = cc*C1; b3 = 1.f;
        if      (m == -1) a1 = s;
        else if (m ==  0) a2 = s;
        else              a0 = s;
    } else {
        if      (m == -2) { a0 = cc*C2XY; b1 = 1.f; }                       // xy
        else if (m == -1) { a1 = cc*C2XY; b2 = 1.f; }                       // yz
        else if (m ==  0) { float s = cc*3.f*C2Z2; a2 = s; b2 = 1.f; c9 = -s/3.f; } // zz-r2/3
        else if (m ==  1) { a2 = cc*C2XY; b0 = 1.f; }                       // zx
        else              { float s = cc*C2D; a0 = s; a1 = s; b0 = 1.f; b1 = -1.f; } // (x+y)(x-y)
    }
    const float nex = -ex * 1.4426950408889634f;  // fold log2(e) for v_exp_f32

    const int w = tid >> 6, ln = tid & 63;

    #pragma unroll
    for (int t = 0; t < TILES; ++t) {
        const int row0 = blockIdx.x * ROWS_PER_BLOCK + t * RPT;
        float (*buf)[NBAS] = s_vals[t];

        // ---- phase 1: evaluate basis `tid` for RPT rows (deep ILP, 128 VGPRs) ----
        #pragma unroll
        for (int r = 0; r < RPT; ++r) {
            float px = inp[(row0 + r)*3 + 0];   // wave-uniform loads
            float py = inp[(row0 + r)*3 + 1];
            float pz = inp[(row0 + r)*3 + 2];
            float x = px - cx, y = py - cy, z = pz - cz;
            float r2 = fmaf(x, x, fmaf(y, y, z * z));
            float A  = fmaf(a0, x, fmaf(a1, y, fmaf(a2, z, a3)));
            float B  = fmaf(b0, x, fmaf(b1, y, fmaf(b2, z, b3)));
            float P  = fmaf(c9, r2, A * B);
            buf[r][tid] = __builtin_exp2f(nex * r2) * P;
        }
        __syncthreads();   // one barrier per tile (covers s_start on t==0)

        // ---- phase 2: wave w owns rows 4w..4w+3 (intra-wave ordering after this) ----
        #pragma unroll
        for (int r = 0; r < 4; ++r) {
            const int row = 4*w + r;
            float4 v = *reinterpret_cast<const float4*>(&buf[row][ln << 2]);
            float e0 = v.x;
            float e1 = e0 + v.y;
            float e2 = e1 + v.z;
            float e3 = e2 + v.w;
            float s    = wave_scan_incl(e3);
            float excl = s - e3;
            *reinterpret_cast<float4*>(&buf[row][ln << 2]) =
                make_float4(e0 + excl, e1 + excl, e2 + excl, e3 + excl);
        }

        // ---- phase 3: boundary diffs, 4 orbitals/lane, 2 rows per pass ----
        #pragma unroll
        for (int g = 0; g < 2; ++g) {
            const int row = 4*w + 2*g + (ln >> 5);   // block-local row in tile
            const int q   = (ln & 31) << 2;
            int st[5];
            #pragma unroll
            for (int k = 0; k < 5; ++k) st[k] = s_start[q + k];
            float p[5];
            #pragma unroll
            for (int k = 0; k < 5; ++k) {
                int idx = st[k] - 1;
                float v = buf[row][idx < 0 ? 0 : idx];
                p[k] = (st[k] > 0) ? v : 0.0f;
            }
            float4 o4 = make_float4(p[1]-p[0], p[2]-p[1], p[3]-p[2], p[4]-p[3]);
            *reinterpret_cast<float4*>(&out[(size_t)(row0 + row) * NORB + q]) = o4;
        }
        // no end-of-tile barrier: next tile writes the OTHER buffer
    }
}

extern "C" void kernel_launch(void* const* d_in, const int* in_sizes, int n_in,
                              void* d_out, int out_size, void* d_ws, size_t ws_size,
                              hipStream_t stream) {
    const float* inp   = (const float*)d_in[0];
    const float* atomc = (const float*)d_in[1];
    const float* bexp  = (const float*)d_in[2];
    const float* bcoef = (const float*)d_in[3];
    const float* bnorm = (const float*)d_in[4];
    // d_in[5] = bas_n (float) — redundant with bas_l, unused
    const int* bl   = (const int*)d_in[6];
    const int* bm   = (const int*)d_in[7];
    const int* bai  = (const int*)d_in[8];
    const int* ictr = (const int*)d_in[9];
    float* out = (float*)d_out;

    hipLaunchKernelGGL(ao_kernel, dim3(NROWS / ROWS_PER_BLOCK), dim3(256), 0, stream,
                       inp, atomc, bexp, bcoef, bnorm, bl, bm, bai, ictr, out);
}